// Round 3
// baseline (210.665 us; speedup 1.0000x reference)
//
#include <hip/hip_runtime.h>

#define DDIM 128

typedef float f4 __attribute__((ext_vector_type(4)));

__global__ __launch_bounds__(256) void wap_main(
    const float* __restrict__ x,
    const float* __restrict__ weights,
    const float* __restrict__ Wg,
    const float* __restrict__ bgp,
    const float* __restrict__ Wm,
    const float* __restrict__ bmp,
    const float* __restrict__ pp,
    const int* __restrict__ index,
    float* __restrict__ denom,
    float* __restrict__ numer,
    int N)
{
    const int lane = threadIdx.x & 63;
    const int rsub = lane & 7;   // row within the 8-row half-chunk
    const int csub = lane >> 3;  // column fragment 0..7 within a row
    const int wid    = (blockIdx.x * blockDim.x + threadIdx.x) >> 6;
    const int nwaves = (gridDim.x * blockDim.x) >> 6;

    const f4* __restrict__ x4   = (const f4*)x;
    const f4* __restrict__ wg4p = (const f4*)Wg;
    const f4* __restrict__ wm4p = (const f4*)Wm;

    // Per-lane fragments of Wg/Wm: float4s at indices csub + 8k, k=0..3
    f4 wg[4], wm[4];
    #pragma unroll
    for (int k = 0; k < 4; ++k) {
        wg[k] = wg4p[csub + 8 * k];
        wm[k] = wm4p[csub + 8 * k];
    }
    const float bg = bgp[0], bm = bmp[0], pv = pp[0];

    // Contiguous ownership: wave `wid` owns chunks [c0, c1) of 16 rows each
    // (contiguous ~61 KB span -> DRAM row-buffer locality).
    const long long C  = ((long long)N + 15) >> 4;
    const long long c0 = (long long)wid * C / nwaves;
    const long long c1 = ((long long)wid + 1) * C / nwaves;

    for (long long c = c0; c < c1; ++c) {
        const long long base = c << 4;
        long long r0 = base + rsub;
        long long r1 = r0 + 8;
        const bool a0 = (r0 < N);
        const bool a1 = (r1 < N);
        const long long r0c = a0 ? r0 : (long long)(N - 1);
        const long long r1c = a1 ? r1 : (long long)(N - 1);

        // Issue all 8 x-loads + w/idx loads before any use (10 indep vmem).
        const f4* __restrict__ xr0 = x4 + r0c * (DDIM / 4);
        const f4* __restrict__ xr1 = x4 + r1c * (DDIM / 4);
        f4 xv0[4], xv1[4];
        #pragma unroll
        for (int k = 0; k < 4; ++k)
            xv0[k] = __builtin_nontemporal_load(&xr0[csub + 8 * k]);
        #pragma unroll
        for (int k = 0; k < 4; ++k)
            xv1[k] = __builtin_nontemporal_load(&xr1[csub + 8 * k]);
        const float w0 = __builtin_nontemporal_load(&weights[r0c]);
        const float w1 = __builtin_nontemporal_load(&weights[r1c]);
        const int   s0 = __builtin_nontemporal_load(&index[r0c]);
        const int   s1 = __builtin_nontemporal_load(&index[r1c]);

        float g0 = 0.f, m0 = 0.f, g1 = 0.f, m1 = 0.f;
        #pragma unroll
        for (int k = 0; k < 4; ++k) {
            g0 = fmaf(xv0[k].x, wg[k].x, g0); g0 = fmaf(xv0[k].y, wg[k].y, g0);
            g0 = fmaf(xv0[k].z, wg[k].z, g0); g0 = fmaf(xv0[k].w, wg[k].w, g0);
            m0 = fmaf(xv0[k].x, wm[k].x, m0); m0 = fmaf(xv0[k].y, wm[k].y, m0);
            m0 = fmaf(xv0[k].z, wm[k].z, m0); m0 = fmaf(xv0[k].w, wm[k].w, m0);
            g1 = fmaf(xv1[k].x, wg[k].x, g1); g1 = fmaf(xv1[k].y, wg[k].y, g1);
            g1 = fmaf(xv1[k].z, wg[k].z, g1); g1 = fmaf(xv1[k].w, wg[k].w, g1);
            m1 = fmaf(xv1[k].x, wm[k].x, m1); m1 = fmaf(xv1[k].y, wm[k].y, m1);
            m1 = fmaf(xv1[k].w, wm[k].w, m1); m1 = fmaf(xv1[k].z, wm[k].z, m1);
        }
        // Butterfly over column-fragment bits (3,4,5): every lane ends with
        // the full dot products of its two rows.
        #pragma unroll
        for (int d = 8; d < 64; d <<= 1) {
            g0 += __shfl_xor(g0, d); m0 += __shfl_xor(m0, d);
            g1 += __shfl_xor(g1, d); m1 += __shfl_xor(m1, d);
        }
        g0 += bg; m0 += bm; g1 += bg; m1 += bm;

        // e = w^p * exp(g); segment-max shift cancels in the final ratio.
        float e0 = __expf(fmaf(pv, __logf(w0), g0));
        float e1 = __expf(fmaf(pv, __logf(w1), g1));
        if (!a0) e0 = 0.f;
        if (!a1) e1 = 0.f;
        const float em0 = e0 * m0, em1 = e1 * m1;

        // Redistribute so virtual lane l in 0..15 holds row (base+l):
        // lanes 8..15 pull row1 values from lanes 0..7.
        const float e1f  = __shfl(e1,  lane & 7);
        const float em1f = __shfl(em1, lane & 7);
        const int   s1f  = __shfl(s1,  lane & 7);
        const bool hi = (lane & 8) != 0;
        float ev  = hi ? e1f  : e0;
        float emv = hi ? em1f : em0;
        int   sv  = hi ? s1f  : s0;

        // Segmented inclusive scan over the 16 virtual rows (index sorted).
        #pragma unroll
        for (int d = 1; d < 16; d <<= 1) {
            float eo  = __shfl_up(ev, d);
            float emo = __shfl_up(emv, d);
            int   so  = __shfl_up(sv, d);
            if (lane >= d && so == sv) { ev += eo; emv += emo; }
        }
        const int sn = __shfl_down(sv, 1);
        if (lane < 16 && (lane == 15 || sn != sv)) {
            atomicAdd(&denom[sv], ev);
            atomicAdd(&numer[sv], emv);
        }
    }
}

__global__ void wap_final(const float* __restrict__ denom,
                          const float* __restrict__ numer,
                          float* __restrict__ out, int S) {
    int i = blockIdx.x * blockDim.x + threadIdx.x;
    if (i < S) out[i] = numer[i] / (denom[i] + 1e-10f);
}

extern "C" void kernel_launch(void* const* d_in, const int* in_sizes, int n_in,
                              void* d_out, int out_size, void* d_ws, size_t ws_size,
                              hipStream_t stream) {
    const float* x       = (const float*)d_in[0];
    const float* weights = (const float*)d_in[1];
    const float* Wg      = (const float*)d_in[2];
    const float* bg      = (const float*)d_in[3];
    const float* Wm      = (const float*)d_in[4];
    const float* bm      = (const float*)d_in[5];
    const float* p       = (const float*)d_in[6];
    const int*   index   = (const int*)d_in[7];  // jnp.int64 w/o x64 => int32

    const int N = in_sizes[0] / DDIM;  // 2,000,000
    const int S = out_size;            // 100,000

    float* denom = (float*)d_ws;
    float* numer = denom + S;

    // Zero the accumulators (capture-legal async memset; saves one kernel node).
    hipMemsetAsync(d_ws, 0, (size_t)2 * S * sizeof(float), stream);
    wap_main<<<2048, 256, 0, stream>>>(x, weights, Wg, bg, Wm, bm, p, index,
                                       denom, numer, N);
    wap_final<<<(S + 255) / 256, 256, 0, stream>>>(denom, numer, (float*)d_out, S);
}

// Round 4
// 171.667 us; speedup vs baseline: 1.2272x; 1.2272x over previous
//
#include <hip/hip_runtime.h>

#define DDIM 128

typedef float f4 __attribute__((ext_vector_type(4)));

__global__ void wap_init(float* __restrict__ acc, int n) {
    int i = blockIdx.x * blockDim.x + threadIdx.x;
    if (i < n) acc[i] = 0.0f;
}

__global__ __launch_bounds__(256) void wap_main(
    const float* __restrict__ x,
    const float* __restrict__ weights,
    const float* __restrict__ Wg,
    const float* __restrict__ bgp,
    const float* __restrict__ Wm,
    const float* __restrict__ bmp,
    const float* __restrict__ pp,
    const int* __restrict__ index,
    float* __restrict__ denom,
    float* __restrict__ numer,
    int N)
{
    const int lane = threadIdx.x & 63;
    const int rsub = lane & 7;   // row within the 8-row half-chunk
    const int csub = lane >> 3;  // column fragment 0..7 within a row
    const int wid    = (blockIdx.x * blockDim.x + threadIdx.x) >> 6;
    const int nwaves = (gridDim.x * blockDim.x) >> 6;

    const f4* __restrict__ x4   = (const f4*)x;
    const f4* __restrict__ wg4p = (const f4*)Wg;
    const f4* __restrict__ wm4p = (const f4*)Wm;

    // Per-lane fragments of Wg/Wm: float4s at indices csub + 8k, k=0..3
    f4 wg[4], wm[4];
    #pragma unroll
    for (int k = 0; k < 4; ++k) {
        wg[k] = wg4p[csub + 8 * k];
        wm[k] = wm4p[csub + 8 * k];
    }
    const float bg = bgp[0], bm = bmp[0], pv = pp[0];

    // Grid-stride over 16-row chunks: at any instant the 2048 waves sweep a
    // contiguous ~16 MB window of x (ideal collective streaming pattern).
    for (long long base = (long long)wid * 16; base < N;
         base += (long long)nwaves * 16) {
        long long r0 = base + rsub;
        long long r1 = r0 + 8;
        const bool a0 = (r0 < N);
        const bool a1 = (r1 < N);
        const long long r0c = a0 ? r0 : (long long)(N - 1);
        const long long r1c = a1 ? r1 : (long long)(N - 1);

        // Issue all 8 x-loads + w/idx loads before any use (10 indep vmem).
        const f4* __restrict__ xr0 = x4 + r0c * (DDIM / 4);
        const f4* __restrict__ xr1 = x4 + r1c * (DDIM / 4);
        f4 xv0[4], xv1[4];
        #pragma unroll
        for (int k = 0; k < 4; ++k)
            xv0[k] = __builtin_nontemporal_load(&xr0[csub + 8 * k]);
        #pragma unroll
        for (int k = 0; k < 4; ++k)
            xv1[k] = __builtin_nontemporal_load(&xr1[csub + 8 * k]);
        const float w0 = __builtin_nontemporal_load(&weights[r0c]);
        const float w1 = __builtin_nontemporal_load(&weights[r1c]);
        const int   s0 = __builtin_nontemporal_load(&index[r0c]);
        const int   s1 = __builtin_nontemporal_load(&index[r1c]);

        float g0 = 0.f, m0 = 0.f, g1 = 0.f, m1 = 0.f;
        #pragma unroll
        for (int k = 0; k < 4; ++k) {
            g0 = fmaf(xv0[k].x, wg[k].x, g0); g0 = fmaf(xv0[k].y, wg[k].y, g0);
            g0 = fmaf(xv0[k].z, wg[k].z, g0); g0 = fmaf(xv0[k].w, wg[k].w, g0);
            m0 = fmaf(xv0[k].x, wm[k].x, m0); m0 = fmaf(xv0[k].y, wm[k].y, m0);
            m0 = fmaf(xv0[k].z, wm[k].z, m0); m0 = fmaf(xv0[k].w, wm[k].w, m0);
            g1 = fmaf(xv1[k].x, wg[k].x, g1); g1 = fmaf(xv1[k].y, wg[k].y, g1);
            g1 = fmaf(xv1[k].z, wg[k].z, g1); g1 = fmaf(xv1[k].w, wg[k].w, g1);
            m1 = fmaf(xv1[k].x, wm[k].x, m1); m1 = fmaf(xv1[k].y, wm[k].y, m1);
            m1 = fmaf(xv1[k].z, wm[k].z, m1); m1 = fmaf(xv1[k].w, wm[k].w, m1);
        }
        // Butterfly over column-fragment bits (3,4,5): every lane ends with
        // the full dot products of its two rows.
        #pragma unroll
        for (int d = 8; d < 64; d <<= 1) {
            g0 += __shfl_xor(g0, d); m0 += __shfl_xor(m0, d);
            g1 += __shfl_xor(g1, d); m1 += __shfl_xor(m1, d);
        }
        g0 += bg; m0 += bm; g1 += bg; m1 += bm;

        // e = w^p * exp(g); segment-max shift cancels in the final ratio.
        float e0 = __expf(fmaf(pv, __logf(w0), g0));
        float e1 = __expf(fmaf(pv, __logf(w1), g1));
        if (!a0) e0 = 0.f;
        if (!a1) e1 = 0.f;
        const float em0 = e0 * m0, em1 = e1 * m1;

        // Redistribute so virtual lane l in 0..15 holds row (base+l):
        // lanes 8..15 pull row1 values from lanes 0..7.
        const float e1f  = __shfl(e1,  lane & 7);
        const float em1f = __shfl(em1, lane & 7);
        const int   s1f  = __shfl(s1,  lane & 7);
        const bool hi = (lane & 8) != 0;
        float ev  = hi ? e1f  : e0;
        float emv = hi ? em1f : em0;
        int   sv  = hi ? s1f  : s0;

        // Segmented inclusive scan over the 16 virtual rows (index sorted).
        #pragma unroll
        for (int d = 1; d < 16; d <<= 1) {
            float eo  = __shfl_up(ev, d);
            float emo = __shfl_up(emv, d);
            int   so  = __shfl_up(sv, d);
            if (lane >= d && so == sv) { ev += eo; emv += emo; }
        }
        const int sn = __shfl_down(sv, 1);
        if (lane < 16 && (lane == 15 || sn != sv)) {
            atomicAdd(&denom[sv], ev);
            atomicAdd(&numer[sv], emv);
        }
    }
}

__global__ void wap_final(const float* __restrict__ denom,
                          const float* __restrict__ numer,
                          float* __restrict__ out, int S) {
    int i = blockIdx.x * blockDim.x + threadIdx.x;
    if (i < S) out[i] = numer[i] / (denom[i] + 1e-10f);
}

extern "C" void kernel_launch(void* const* d_in, const int* in_sizes, int n_in,
                              void* d_out, int out_size, void* d_ws, size_t ws_size,
                              hipStream_t stream) {
    const float* x       = (const float*)d_in[0];
    const float* weights = (const float*)d_in[1];
    const float* Wg      = (const float*)d_in[2];
    const float* bg      = (const float*)d_in[3];
    const float* Wm      = (const float*)d_in[4];
    const float* bm      = (const float*)d_in[5];
    const float* p       = (const float*)d_in[6];
    const int*   index   = (const int*)d_in[7];  // jnp.int64 w/o x64 => int32

    const int N = in_sizes[0] / DDIM;  // 2,000,000
    const int S = out_size;            // 100,000

    float* denom = (float*)d_ws;
    float* numer = denom + S;

    wap_init<<<(2 * S + 255) / 256, 256, 0, stream>>>(denom, 2 * S);
    wap_main<<<2048, 256, 0, stream>>>(x, weights, Wg, bg, Wm, bm, p, index,
                                       denom, numer, N);
    wap_final<<<(S + 255) / 256, 256, 0, stream>>>(denom, numer, (float*)d_out, S);
}